// Round 7
// baseline (113.015 us; speedup 1.0000x reference)
//
#include <hip/hip_runtime.h>
#include <stdint.h>

#define BB      32
#define NN      2000
#define TOPK_   110
#define NBIN    2048

// ---------------------------------------------------------------------------
// Weight folding: scores collapse to a bilinear form in the raw 3-D points:
//   score(n,m)*log2e/sqrt5 = (g_n + vp) . p_m + (row-const, cancels in softmax)
//   g_n = Gp^T p_n,  Gp = pf*(WiWq)(WiWk)^T,  vp = pf*cq(WiWk)^T
// ---------------------------------------------------------------------------
__device__ __forceinline__ void fold_weights(
    const float* __restrict__ Wi, const float* __restrict__ bi,
    const float* __restrict__ Wq, const float* __restrict__ bq,
    const float* __restrict__ Wk, const float* __restrict__ bk,
    float Gp[3][3], float vp[3])
{
    const float pf = 0.44721359549995793f * 1.4426950408889634f; // 1/sqrt5*log2e
    float Mq[15], Mk[15], cq[5];
#pragma unroll
    for (int d = 0; d < 5; ++d) {
        float s = bq[d];
#pragma unroll
        for (int k = 0; k < 5; ++k) s += bi[k] * Wq[k * 5 + d];
        cq[d] = s;
    }
#pragma unroll
    for (int i = 0; i < 3; ++i)
#pragma unroll
        for (int d = 0; d < 5; ++d) {
            float sq = 0.f, sk = 0.f;
#pragma unroll
            for (int k = 0; k < 5; ++k) {
                sq += Wi[i * 5 + k] * Wq[k * 5 + d];
                sk += Wi[i * 5 + k] * Wk[k * 5 + d];
            }
            Mq[i * 5 + d] = sq;
            Mk[i * 5 + d] = sk;
        }
#pragma unroll
    for (int i = 0; i < 3; ++i)
#pragma unroll
        for (int j = 0; j < 3; ++j) {
            float s = 0.f;
#pragma unroll
            for (int d = 0; d < 5; ++d) s += Mq[i * 5 + d] * Mk[j * 5 + d];
            Gp[i][j] = s * pf;
        }
#pragma unroll
    for (int j = 0; j < 3; ++j) {
        float s = 0.f;
#pragma unroll
        for (int d = 0; d < 5; ++d) s += cq[d] * Mk[j * 5 + d];
        vp[j] = s * pf;
    }
}

// ---------------------------------------------------------------------------
// Kernel 1: diag[b,row] = exp2(h_row.p_row) / sum_m exp2(h_row.p_m)
// grid (16 row-chunks, 32 batches), block 1024 (16 waves).
// Each lane carries 2 rows (h = g+vp held in 6 VGPRs); wave w sums over
// m in [125w, 125w+125). p_m is wave-uniform -> scalar (SMEM/L1) loads,
// NO LDS staging, no ds_read in the inner loop. 8 KB LDS reduce buffer.
// ---------------------------------------------------------------------------
__global__ __launch_bounds__(1024) void k_diag(
    const float* __restrict__ in_mat,                       // [B,N,3]
    const float* __restrict__ Wi, const float* __restrict__ bi,
    const float* __restrict__ Wq, const float* __restrict__ bq,
    const float* __restrict__ Wk, const float* __restrict__ bk,
    float* __restrict__ diag)                               // [B,N] in d_ws
{
    __shared__ float partial[16][128];   // 8 KB

    const int b   = blockIdx.y;
    const int rc  = blockIdx.x;               // row-chunk of 128
    const int t   = threadIdx.x;
    const int wid = t >> 6;
    const int lane = t & 63;
    const float* inb = in_mat + (size_t)b * NN * 3;

    float Gp[3][3], vp[3];
    fold_weights(Wi, bi, Wq, bq, Wk, bk, Gp, vp);

    // this lane's 2 rows: h_r = Gp^T p_r + vp
    float h[2][3];
#pragma unroll
    for (int r = 0; r < 2; ++r) {
        const int row = rc * 128 + r * 64 + lane;
        float p0 = 0.f, p1 = 0.f, p2 = 0.f;
        if (row < NN) {
            p0 = inb[row * 3 + 0];
            p1 = inb[row * 3 + 1];
            p2 = inb[row * 3 + 2];
        }
#pragma unroll
        for (int j = 0; j < 3; ++j)
            h[r][j] = p0 * Gp[0][j] + p1 * Gp[1][j] + p2 * Gp[2][j] + vp[j];
    }

    // exp2-sum over this wave's m-chunk; p_m wave-uniform -> scalar loads
    float acc0 = 0.f, acc1 = 0.f;
    const int m0 = wid * 125;
#pragma unroll 5
    for (int m = m0; m < m0 + 125; ++m) {
        const float px = inb[m * 3 + 0];
        const float py = inb[m * 3 + 1];
        const float pz = inb[m * 3 + 2];
        const float e0 = fmaf(h[0][0], px, fmaf(h[0][1], py, h[0][2] * pz));
        const float e1 = fmaf(h[1][0], px, fmaf(h[1][1], py, h[1][2] * pz));
        acc0 += __builtin_amdgcn_exp2f(e0);
        acc1 += __builtin_amdgcn_exp2f(e1);
    }
    partial[wid][lane]      = acc0;
    partial[wid][64 + lane] = acc1;
    __syncthreads();

    // final reduce (fixed wave order, deterministic) + write diag
    if (t < 128) {
        const int row = rc * 128 + t;
        if (row < NN) {
            float sum = partial[0][t];
#pragma unroll
            for (int w = 1; w < 16; ++w) sum += partial[w][t];
            const float p0 = inb[row * 3 + 0];
            const float p1 = inb[row * 3 + 1];
            const float p2 = inb[row * 3 + 2];
            float hh[3];
#pragma unroll
            for (int j = 0; j < 3; ++j)
                hh[j] = p0 * Gp[0][j] + p1 * Gp[1][j] + p2 * Gp[2][j] + vp[j];
            const float e = fmaf(hh[0], p0, fmaf(hh[1], p1, hh[2] * p2));
            diag[(size_t)b * NN + row] = __builtin_amdgcn_exp2f(e) / sum;
        }
    }
}

// ---------------------------------------------------------------------------
// Kernel 2: per batch — group argmax, centroid, distances, top-110 via
// histogram-select + rank-by-counting. grid 32, block 1024.
// ---------------------------------------------------------------------------
__global__ __launch_bounds__(1024) void k_select(
    const float* __restrict__ in_mat,     // [B,N,3]
    const float* __restrict__ diag,       // [B,N]
    float* __restrict__ out)              // [B,110,3]
{
    __shared__ unsigned long long keys[2048];       // 16 KB
    __shared__ unsigned long long cand[2048];       // 16 KB
    __shared__ unsigned int hist[NBIN];             //  8 KB
    __shared__ unsigned int sA[NBIN];               //  8 KB
    __shared__ unsigned int sB[NBIN];               //  8 KB
    __shared__ float        wv[16];
    __shared__ int          wi_[16];
    __shared__ float        centroid[3];
    __shared__ int          thrBin, cnt;

    const int b = blockIdx.x;
    const int t = threadIdx.x;
    const float* dg  = diag + (size_t)b * NN;
    const float* inb = in_mat + (size_t)b * NN * 3;

    hist[t] = 0u; hist[t + 1024] = 0u;
    if (t == 0) cnt = 0;

    // group sums (5 consecutive diag, reference order) + argmax
    float v = -INFINITY; int idx = 0x7fffffff;
    if (t < NN / 5) {
        float s = dg[t * 5 + 0];
        s += dg[t * 5 + 1];
        s += dg[t * 5 + 2];
        s += dg[t * 5 + 3];
        s += dg[t * 5 + 4];
        v = s; idx = t;
    }
#pragma unroll
    for (int off = 32; off > 0; off >>= 1) {
        const float ov = __shfl_down(v, off);
        const int   oi = __shfl_down(idx, off);
        if (ov > v || (ov == v && oi < idx)) { v = ov; idx = oi; }
    }
    if ((t & 63) == 0) { wv[t >> 6] = v; wi_[t >> 6] = idx; }
    __syncthreads();

    if (t == 0) {
        float bv = wv[0]; int bidx = wi_[0];
#pragma unroll
        for (int w = 1; w < 16; ++w) {
            if (wv[w] > bv || (wv[w] == bv && wi_[w] < bidx)) {
                bv = wv[w]; bidx = wi_[w];
            }
        }
        // centroid of winning group (bit-exact numpy mean: rn adds, /5)
        const int base = bidx * 5;
#pragma unroll
        for (int d = 0; d < 3; ++d) {
            float s = inb[(base + 0) * 3 + d];
            s = __fadd_rn(s, inb[(base + 1) * 3 + d]);
            s = __fadd_rn(s, inb[(base + 2) * 3 + d]);
            s = __fadd_rn(s, inb[(base + 3) * 3 + d]);
            s = __fadd_rn(s, inb[(base + 4) * 3 + d]);
            centroid[d] = __fdiv_rn(s, 5.0f);
        }
    }
    __syncthreads();

    const float c0 = centroid[0], c1 = centroid[1], c2 = centroid[2];

    // distances -> keys + histogram on dist_bits[30:20]
#pragma unroll
    for (int r = 0; r < 2; ++r) {
        const int n = r * 1024 + t;
        if (n < NN) {
            const float dx = inb[n * 3 + 0] - c0;
            const float dy = inb[n * 3 + 1] - c1;
            const float dz = inb[n * 3 + 2] - c2;
            // no FMA contraction: bit-exact vs np.linalg.norm ((x2+y2)+z2)
            const float d2 = __fadd_rn(__fadd_rn(__fmul_rn(dx, dx),
                                                 __fmul_rn(dy, dy)),
                                       __fmul_rn(dz, dz));
            const float dist = __fsqrt_rn(d2);
            const unsigned int db = __float_as_uint(dist);
            keys[n] = ((unsigned long long)db << 32) | (unsigned int)n;
            atomicAdd(&hist[db >> 20], 1u);        // sign=0 -> bin < 2048
        }
    }
    __syncthreads();

    // inclusive scan over 2048 bins (ping-pong Hillis-Steele)
    unsigned int* src = hist;
    unsigned int* dst = sA;
    for (int stride = 1; stride < NBIN; stride <<= 1) {
#pragma unroll
        for (int r = 0; r < 2; ++r) {
            const int i = r * 1024 + t;
            dst[i] = src[i] + ((i >= stride) ? src[i - stride] : 0u);
        }
        __syncthreads();
        unsigned int* tmp = (dst == sA) ? sB : sA;
        src = dst; dst = (src == hist) ? sA : tmp;
    }
    const unsigned int* cum = src;

    // threshold bin: first bin with cum >= 110 (unique writer)
#pragma unroll
    for (int r = 0; r < 2; ++r) {
        const int i = r * 1024 + t;
        if (cum[i] >= TOPK_ && (i == 0 || cum[i - 1] < TOPK_)) thrBin = i;
    }
    __syncthreads();

    // compact candidates (all elements in bins <= thrBin)
    const int T = thrBin;
#pragma unroll
    for (int r = 0; r < 2; ++r) {
        const int n = r * 1024 + t;
        if (n < NN) {
            const unsigned long long k = keys[n];
            if ((int)(k >> 52) <= T) {
                const int pos = atomicAdd(&cnt, 1);
                cand[pos] = k;
            }
        }
    }
    __syncthreads();

    // rank-by-counting among candidates; rank == global rank (keys distinct)
    const int C = cnt;
    for (int i = t; i < C; i += 1024) {
        const unsigned long long ki = cand[i];
        int rank = 0;
        for (int j = 0; j < C; ++j) rank += (cand[j] < ki);
        if (rank < TOPK_) {
            const int n = (int)(unsigned int)(ki & 0xFFFFFFFFull);
            out[((size_t)b * TOPK_ + rank) * 3 + 0] = inb[n * 3 + 0];
            out[((size_t)b * TOPK_ + rank) * 3 + 1] = inb[n * 3 + 1];
            out[((size_t)b * TOPK_ + rank) * 3 + 2] = inb[n * 3 + 2];
        }
    }
}

// ---------------------------------------------------------------------------
extern "C" void kernel_launch(void* const* d_in, const int* in_sizes, int n_in,
                              void* d_out, int out_size, void* d_ws, size_t ws_size,
                              hipStream_t stream) {
    const float* in_mat = (const float*)d_in[0];
    const float* Wi = (const float*)d_in[1];
    const float* bi = (const float*)d_in[2];
    const float* Wq = (const float*)d_in[3];
    const float* bq = (const float*)d_in[4];
    const float* Wk = (const float*)d_in[5];
    const float* bk = (const float*)d_in[6];
    // Wv, bv, Wo, bo (d_in[7..10]) are dead code in the reference.

    float* diag = (float*)d_ws;               // B*N floats = 256 KB
    float* out  = (float*)d_out;

    k_diag<<<dim3(16, BB), 1024, 0, stream>>>(
        in_mat, Wi, bi, Wq, bq, Wk, bk, diag);
    k_select<<<BB, 1024, 0, stream>>>(in_mat, diag, out);
}

// Round 8
// 106.488 us; speedup vs baseline: 1.0613x; 1.0613x over previous
//
#include <hip/hip_runtime.h>
#include <stdint.h>

#define BB      32
#define NN      2000
#define TOPK_   110
#define NBIN    2048

// ---------------------------------------------------------------------------
// Weight folding: scores collapse to a bilinear form in the raw 3-D points:
//   score(n,m)*log2e/sqrt5 = (g_n + vp) . p_m + (row-const, cancels in softmax)
//   g_n = Gp^T p_n,  Gp = pf*(WiWq)(WiWk)^T,  vp = pf*cq(WiWk)^T
// ---------------------------------------------------------------------------
__device__ __forceinline__ void fold_weights(
    const float* __restrict__ Wi, const float* __restrict__ bi,
    const float* __restrict__ Wq, const float* __restrict__ bq,
    const float* __restrict__ Wk, const float* __restrict__ bk,
    float Gp[3][3], float vp[3])
{
    const float pf = 0.44721359549995793f * 1.4426950408889634f; // 1/sqrt5*log2e
    float Mq[15], Mk[15], cq[5];
#pragma unroll
    for (int d = 0; d < 5; ++d) {
        float s = bq[d];
#pragma unroll
        for (int k = 0; k < 5; ++k) s += bi[k] * Wq[k * 5 + d];
        cq[d] = s;
    }
#pragma unroll
    for (int i = 0; i < 3; ++i)
#pragma unroll
        for (int d = 0; d < 5; ++d) {
            float sq = 0.f, sk = 0.f;
#pragma unroll
            for (int k = 0; k < 5; ++k) {
                sq += Wi[i * 5 + k] * Wq[k * 5 + d];
                sk += Wi[i * 5 + k] * Wk[k * 5 + d];
            }
            Mq[i * 5 + d] = sq;
            Mk[i * 5 + d] = sk;
        }
#pragma unroll
    for (int i = 0; i < 3; ++i)
#pragma unroll
        for (int j = 0; j < 3; ++j) {
            float s = 0.f;
#pragma unroll
            for (int d = 0; d < 5; ++d) s += Mq[i * 5 + d] * Mk[j * 5 + d];
            Gp[i][j] = s * pf;
        }
#pragma unroll
    for (int j = 0; j < 3; ++j) {
        float s = 0.f;
#pragma unroll
        for (int d = 0; d < 5; ++d) s += cq[d] * Mk[j * 5 + d];
        vp[j] = s * pf;
    }
}

// ---------------------------------------------------------------------------
// Kernel 1: diag[b,row] = exp2(h_row.p_row) / sum_m exp2(h_row.p_m)
// grid (8 row-chunks, 32 batches), block 1024 (16 waves).
// SoA points in LDS; wave w owns the ALIGNED m-chunk [128w, 128w+128) (pads
// m>=2000 hold zeros -> exp2(0)=1 each; wave 15 subtracts its 48 pads).
// 4 rows/lane; per quad of 4 m's: 3 uniform ds_read_b128 (broadcast).
// ---------------------------------------------------------------------------
__global__ __launch_bounds__(1024) void k_diag(
    const float* __restrict__ in_mat,                       // [B,N,3]
    const float* __restrict__ Wi, const float* __restrict__ bi,
    const float* __restrict__ Wq, const float* __restrict__ bq,
    const float* __restrict__ Wk, const float* __restrict__ bk,
    float* __restrict__ diag)                               // [B,N] in d_ws
{
    __shared__ float xs[2048], ys[2048], zs[2048];   // 24 KB (SoA, 16B-aligned)
    __shared__ float partial[16][256];               // 16 KB

    const int b    = blockIdx.y;
    const int rc   = blockIdx.x;              // row-chunk of 256
    const int t    = threadIdx.x;
    const int wid  = t >> 6;
    const int lane = t & 63;
    const float* inb = in_mat + (size_t)b * NN * 3;

    float Gp[3][3], vp[3];
    fold_weights(Wi, bi, Wq, bq, Wk, bk, Gp, vp);

    // stage SoA points (pads = 0)
#pragma unroll
    for (int r = 0; r < 2; ++r) {
        const int n = r * 1024 + t;
        float p0 = 0.f, p1 = 0.f, p2 = 0.f;
        if (n < NN) {
            p0 = inb[n * 3 + 0];
            p1 = inb[n * 3 + 1];
            p2 = inb[n * 3 + 2];
        }
        xs[n] = p0; ys[n] = p1; zs[n] = p2;
    }

    // this lane's 4 rows: h_r = Gp^T p_r + vp
    float h[4][3];
#pragma unroll
    for (int r = 0; r < 4; ++r) {
        const int row = rc * 256 + r * 64 + lane;
        float p0 = 0.f, p1 = 0.f, p2 = 0.f;
        if (row < NN) {
            p0 = inb[row * 3 + 0];
            p1 = inb[row * 3 + 1];
            p2 = inb[row * 3 + 2];
        }
#pragma unroll
        for (int j = 0; j < 3; ++j)
            h[r][j] = p0 * Gp[0][j] + p1 * Gp[1][j] + p2 * Gp[2][j] + vp[j];
    }
    __syncthreads();

    // exp2-sum over this wave's aligned m-chunk: 32 quads of 4 m's
    float acc[4] = {0.f, 0.f, 0.f, 0.f};
    const int m0 = wid * 128;
#pragma unroll 2
    for (int mq = 0; mq < 32; ++mq) {
        const int m = m0 + mq * 4;
        const float4 X = *(const float4*)&xs[m];   // broadcast ds_read_b128
        const float4 Y = *(const float4*)&ys[m];
        const float4 Z = *(const float4*)&zs[m];
#pragma unroll
        for (int r = 0; r < 4; ++r) {
            acc[r] += __builtin_amdgcn_exp2f(
                fmaf(h[r][0], X.x, fmaf(h[r][1], Y.x, h[r][2] * Z.x)));
            acc[r] += __builtin_amdgcn_exp2f(
                fmaf(h[r][0], X.y, fmaf(h[r][1], Y.y, h[r][2] * Z.y)));
            acc[r] += __builtin_amdgcn_exp2f(
                fmaf(h[r][0], X.z, fmaf(h[r][1], Y.z, h[r][2] * Z.z)));
            acc[r] += __builtin_amdgcn_exp2f(
                fmaf(h[r][0], X.w, fmaf(h[r][1], Y.w, h[r][2] * Z.w)));
        }
    }
    // wave 15's chunk [1920,2048) has 48 pads, each contributing exp2(0)=1
    if (wid == 15) {
#pragma unroll
        for (int r = 0; r < 4; ++r) acc[r] -= 48.0f;
    }
#pragma unroll
    for (int r = 0; r < 4; ++r)
        partial[wid][r * 64 + lane] = acc[r];
    __syncthreads();

    // final reduce (fixed wave order, deterministic) + write diag
    if (t < 256) {
        const int row = rc * 256 + t;
        if (row < NN) {
            float sum = partial[0][t];
#pragma unroll
            for (int w = 1; w < 16; ++w) sum += partial[w][t];
            const float p0 = xs[row], p1 = ys[row], p2 = zs[row];
            float hh[3];
#pragma unroll
            for (int j = 0; j < 3; ++j)
                hh[j] = p0 * Gp[0][j] + p1 * Gp[1][j] + p2 * Gp[2][j] + vp[j];
            const float e = fmaf(hh[0], p0, fmaf(hh[1], p1, hh[2] * p2));
            diag[(size_t)b * NN + row] = __builtin_amdgcn_exp2f(e) / sum;
        }
    }
}

// ---------------------------------------------------------------------------
// Kernel 2: per batch — group argmax, centroid, distances, top-110 via
// histogram-select (2-barrier wave scan) + rank-by-counting. grid 32, blk 1024.
// ---------------------------------------------------------------------------
__global__ __launch_bounds__(1024) void k_select(
    const float* __restrict__ in_mat,     // [B,N,3]
    const float* __restrict__ diag,       // [B,N]
    float* __restrict__ out)              // [B,110,3]
{
    __shared__ unsigned long long keys[2048];       // 16 KB
    __shared__ unsigned long long cand[2048];       // 16 KB
    __shared__ unsigned int hist[NBIN];             //  8 KB
    __shared__ unsigned int cum[NBIN];              //  8 KB
    __shared__ unsigned int wtot[16];
    __shared__ float        wv[16];
    __shared__ int          wi_[16];
    __shared__ float        centroid[3];
    __shared__ int          thrBin, cnt;

    const int b    = blockIdx.x;
    const int t    = threadIdx.x;
    const int wid  = t >> 6;
    const int lane = t & 63;
    const float* dg  = diag + (size_t)b * NN;
    const float* inb = in_mat + (size_t)b * NN * 3;

    hist[t] = 0u; hist[t + 1024] = 0u;
    if (t == 0) cnt = 0;

    // group sums (5 consecutive diag, reference order) + argmax
    float v = -INFINITY; int idx = 0x7fffffff;
    if (t < NN / 5) {
        float s = dg[t * 5 + 0];
        s += dg[t * 5 + 1];
        s += dg[t * 5 + 2];
        s += dg[t * 5 + 3];
        s += dg[t * 5 + 4];
        v = s; idx = t;
    }
#pragma unroll
    for (int off = 32; off > 0; off >>= 1) {
        const float ov = __shfl_down(v, off);
        const int   oi = __shfl_down(idx, off);
        if (ov > v || (ov == v && oi < idx)) { v = ov; idx = oi; }
    }
    if (lane == 0) { wv[wid] = v; wi_[wid] = idx; }
    __syncthreads();

    if (t == 0) {
        float bv = wv[0]; int bidx = wi_[0];
#pragma unroll
        for (int w = 1; w < 16; ++w) {
            if (wv[w] > bv || (wv[w] == bv && wi_[w] < bidx)) {
                bv = wv[w]; bidx = wi_[w];
            }
        }
        // centroid of winning group (bit-exact numpy mean: rn adds, /5)
        const int base = bidx * 5;
#pragma unroll
        for (int d = 0; d < 3; ++d) {
            float s = inb[(base + 0) * 3 + d];
            s = __fadd_rn(s, inb[(base + 1) * 3 + d]);
            s = __fadd_rn(s, inb[(base + 2) * 3 + d]);
            s = __fadd_rn(s, inb[(base + 3) * 3 + d]);
            s = __fadd_rn(s, inb[(base + 4) * 3 + d]);
            centroid[d] = __fdiv_rn(s, 5.0f);
        }
    }
    __syncthreads();

    const float c0 = centroid[0], c1 = centroid[1], c2 = centroid[2];

    // distances -> keys + histogram on dist_bits[31:20] (sign 0 -> bin < 2048)
#pragma unroll
    for (int r = 0; r < 2; ++r) {
        const int n = r * 1024 + t;
        if (n < NN) {
            const float dx = inb[n * 3 + 0] - c0;
            const float dy = inb[n * 3 + 1] - c1;
            const float dz = inb[n * 3 + 2] - c2;
            // no FMA contraction: bit-exact vs np.linalg.norm ((x2+y2)+z2)
            const float d2 = __fadd_rn(__fadd_rn(__fmul_rn(dx, dx),
                                                 __fmul_rn(dy, dy)),
                                       __fmul_rn(dz, dz));
            const float dist = __fsqrt_rn(d2);
            const unsigned int db = __float_as_uint(dist);
            keys[n] = ((unsigned long long)db << 32) | (unsigned int)n;
            atomicAdd(&hist[db >> 20], 1u);
        }
    }
    __syncthreads();

    // inclusive scan over 2048 bins: per-wave shuffle scan + wave offsets
    {
        const int base = wid * 128;
        unsigned s0 = hist[base + lane];
        unsigned s1 = hist[base + 64 + lane];
#pragma unroll
        for (int off = 1; off < 64; off <<= 1) {
            const unsigned n0 = __shfl_up(s0, off);
            const unsigned n1 = __shfl_up(s1, off);
            if (lane >= off) { s0 += n0; s1 += n1; }
        }
        const unsigned t0 = __shfl(s0, 63);
        s1 += t0;                                  // second half offset
        if (lane == 63) wtot[wid] = s1;            // wave total
        __syncthreads();
        unsigned off_ = 0;
        for (int w = 0; w < wid; ++w) off_ += wtot[w];
        cum[base + lane]      = s0 + off_;
        cum[base + 64 + lane] = s1 + off_;
    }
    __syncthreads();

    // threshold bin: first bin with cum >= 110 (unique writer)
#pragma unroll
    for (int r = 0; r < 2; ++r) {
        const int i = r * 1024 + t;
        if (cum[i] >= TOPK_ && (i == 0 || cum[i - 1] < TOPK_)) thrBin = i;
    }
    __syncthreads();

    // compact candidates (all elements in bins <= thrBin)
    const int T = thrBin;
#pragma unroll
    for (int r = 0; r < 2; ++r) {
        const int n = r * 1024 + t;
        if (n < NN) {
            const unsigned long long k = keys[n];
            if ((int)(k >> 52) <= T) {
                const int pos = atomicAdd(&cnt, 1);
                cand[pos] = k;
            }
        }
    }
    __syncthreads();

    // rank-by-counting among candidates; rank == global rank (keys distinct)
    const int C = cnt;
    for (int i = t; i < C; i += 1024) {
        const unsigned long long ki = cand[i];
        int rank = 0;
        for (int j = 0; j < C; ++j) rank += (cand[j] < ki);
        if (rank < TOPK_) {
            const int n = (int)(unsigned int)(ki & 0xFFFFFFFFull);
            out[((size_t)b * TOPK_ + rank) * 3 + 0] = inb[n * 3 + 0];
            out[((size_t)b * TOPK_ + rank) * 3 + 1] = inb[n * 3 + 1];
            out[((size_t)b * TOPK_ + rank) * 3 + 2] = inb[n * 3 + 2];
        }
    }
}

// ---------------------------------------------------------------------------
extern "C" void kernel_launch(void* const* d_in, const int* in_sizes, int n_in,
                              void* d_out, int out_size, void* d_ws, size_t ws_size,
                              hipStream_t stream) {
    const float* in_mat = (const float*)d_in[0];
    const float* Wi = (const float*)d_in[1];
    const float* bi = (const float*)d_in[2];
    const float* Wq = (const float*)d_in[3];
    const float* bq = (const float*)d_in[4];
    const float* Wk = (const float*)d_in[5];
    const float* bk = (const float*)d_in[6];
    // Wv, bv, Wo, bo (d_in[7..10]) are dead code in the reference.

    float* diag = (float*)d_ws;               // B*N floats = 256 KB
    float* out  = (float*)d_out;

    k_diag<<<dim3(8, BB), 1024, 0, stream>>>(
        in_mat, Wi, bi, Wq, bq, Wk, bk, diag);
    k_select<<<BB, 1024, 0, stream>>>(in_mat, diag, out);
}